// Round 13
// baseline (8403.562 us; speedup 1.0000x reference)
//
#include <hip/hip_runtime.h>
#include <hip/hip_bf16.h>
#include <stdint.h>

// Problem dims
#define BB 64     // batch
#define SS 512    // seq len
#define HH 512    // hidden
#define DD 300    // embed dim
#define DP 320    // embed dim padded to K%32==0

typedef __attribute__((ext_vector_type(8))) short short8;      // 8 x bf16
typedef __attribute__((ext_vector_type(4))) float f32x4;

__device__ __forceinline__ unsigned short f2bf(float f) {
  unsigned u = __builtin_bit_cast(unsigned, f);
  u += 0x7fffu + ((u >> 16) & 1u);       // RNE
  return (unsigned short)(u >> 16);
}
__device__ __forceinline__ float sigm(float x) { return 1.f / (1.f + __expf(-x)); }
__device__ __forceinline__ float tanh_f(float x) {
  float t = __expf(-2.f * fabsf(x));
  float r = (1.f - t) / (1.f + t);
  return x < 0.f ? -r : r;
}

// 16B loads. sc1 = agent scope (MALL-coherent). NOT valid until s_waitcnt vmcnt(0).
__device__ __forceinline__ short8 load_frag(const unsigned short* p) {
  short8 r;
  asm volatile("global_load_dwordx4 %0, %1, off" : "=v"(r) : "v"(p));
  return r;
}
__device__ __forceinline__ short8 load_frag_sc1(const unsigned short* p) {
  short8 r;
  asm volatile("global_load_dwordx4 %0, %1, off sc1" : "=v"(r) : "v"(p));
  return r;
}
__device__ __forceinline__ unsigned ld_seq(const unsigned int* p) {
  return __hip_atomic_load(p, __ATOMIC_RELAXED, __HIP_MEMORY_SCOPE_AGENT);
}
__device__ __forceinline__ void st_seq(unsigned int* p, unsigned v) {
  __hip_atomic_store(p, v, __ATOMIC_RELAXED, __HIP_MEMORY_SCOPE_AGENT);
}

// ---------------- workspace layout (bytes) ----------------
// Frag-ready h panels (64KB): element (b,c) at u16 addr (c>>5)*2048 + (b>>4)*512
// + ((c>>3)&3)*128 + (b&15)*8 + (c&7); A-frag (m,kblk) = kblk*2048+m*512+lane*8.
// MERGED design: 64 blocks, each owns gate rows of BOTH layers for h-cells
// [8*lblk, 8*lblk+8). Iter t: L0 step t (t<512) + L1 step t-1 (t>=1).
// Rings depth 2: h1(j) slot j&1, h2(j) slot j&1. ONE seq word per block;
// seq[b]=j+1 after iter j. Poll seq>=t at iter t bounds skew < 1 iter, which
// makes ring-2 reuse safe (reads of the overwritten slot happened at iter t-1).
#define OFF_SEQ   0u          // seq[64], 64B spaced -> 4096; reserved 8192
#define OFF_H1    8192u       // h1 ring [2][32768 u16] -> 131072
#define OFF_H2    139264u     // h2 ring [2][32768 u16] -> 131072
#define OFF_C2    270336u     // c2 [64][512] f32 -> 131072
#define OFF_XE    401408u     // xe bf16 frag layout [512][20480 u16] -> 20971520
#define OFF_W0    21372928u   // Wp0 [2048][832] bf16 -> 3407872
#define OFF_W1    24780800u   // Wp1 [2048][1024] bf16 -> 4194304
#define OFF_B0    28975104u   // bias0p [2048] f32
#define OFF_B1    28983296u   // bias1p [2048] f32
#define MEMSET_BYTES 270336u  // seq + both h rings (slot1 = h(-1) = 0)

// ---------------- weight prep (row-major Wp) ----------------
// grow = lblk*32 + l, gate = l>>3 (i,f,g,o), orig = gate*512 + lblk*8 + (l&7).
// Wp0 row: [ W_hh0 | W_ih0 | pad ] (A = [h1_prev | x_t]); Wp1 row: [ W_ih1 | W_hh1 ].
__global__ void prep_weights(const float* __restrict__ Wih0, const float* __restrict__ Whh0,
                             const float* __restrict__ bih0, const float* __restrict__ bhh0,
                             const float* __restrict__ Wih1, const float* __restrict__ Whh1,
                             const float* __restrict__ bih1, const float* __restrict__ bhh1,
                             unsigned short* __restrict__ Wp0, unsigned short* __restrict__ Wp1,
                             float* __restrict__ b0p, float* __restrict__ b1p)
{
  int idx = blockIdx.x * 256 + threadIdx.x;   // over 2048*1024
  int grow = idx >> 10;
  int k1 = idx & 1023;
  int l = grow & 31;
  int lb = grow >> 5;
  int gate = l >> 3;
  int orig = gate * 512 + lb * 8 + (l & 7);
  float v1 = (k1 < 512) ? Wih1[orig * 512 + k1] : Whh1[orig * 512 + (k1 - 512)];
  Wp1[idx] = f2bf(v1);
  if (k1 < 832) {
    float v0;
    if (k1 < 512)      v0 = Whh0[orig * 512 + k1];
    else if (k1 < 812) v0 = Wih0[orig * 300 + (k1 - 512)];
    else               v0 = 0.f;
    Wp0[grow * 832 + k1] = f2bf(v0);
  }
  if (k1 == 0) {
    b0p[grow] = bih0[orig] + bhh0[orig];
    b1p[grow] = bih1[orig] + bhh1[orig];
  }
}

// ---------------- embedding gather -> bf16 frag layout ----------------
__global__ void gather_xe(const int* __restrict__ x, const float* __restrict__ emb,
                          unsigned short* __restrict__ xe)
{
  int idx = blockIdx.x * 256 + threadIdx.x;   // SS*BB*DP = 10485760
  int dk = idx % DP;
  int rem = idx / DP;
  int b = rem % BB;
  int t = rem / BB;
  int tok = x[b * SS + t];
  float v = (dk < DD) ? emb[(size_t)tok * DD + dk] : 0.f;
  size_t ua = (size_t)t * 20480 + (size_t)(dk >> 5) * 2048 + (size_t)(b >> 4) * 512
            + (size_t)((dk >> 3) & 3) * 128 + (size_t)(b & 15) * 8 + (dk & 7);
  xe[ua] = f2bf(v);
}

// ---------------- merged 2-layer persistent scan (64 blocks x 512 thr) ----------------
// Wave w: m = w&3 (batch tile), q = w>>2 (khalf). q0 loads h1(t-1) frags
// (shared A for BOTH layers' MFMAs); q1 loads xe(t) (cached, pre-poll) for L0
// and h2(t-2) (sc1) for L1. One poll + 3 barriers per iter; one seq signal.
__attribute__((amdgpu_waves_per_eu(2, 2)))
__global__ void __launch_bounds__(512)
lstm_scan(const unsigned short* __restrict__ xe,
          const unsigned short* __restrict__ Wp0,
          const unsigned short* __restrict__ Wp1,
          const float* __restrict__ b0p, const float* __restrict__ b1p,
          unsigned short* __restrict__ h1r, unsigned short* __restrict__ h2r,
          float* __restrict__ c2, unsigned int* __restrict__ seq)
{
  __shared__ float gl0[2][64][36];   // L0 gate staging [khalf][batch][gate col]
  __shared__ float gl1[2][64][36];   // L1 gate staging
  __shared__ float bias0_sm[32], bias1_sm[32];

  const int lblk = blockIdx.x;
  const int tid  = threadIdx.x;
  const int lane = tid & 63;
  const int wave = tid >> 6;
  const int lrow = lane & 15;
  const int m    = wave & 3;
  const int q    = wave >> 2;

  if (tid < 32)       bias0_sm[tid]      = b0p[lblk * 32 + tid];
  else if (tid < 64)  bias1_sm[tid - 32] = b1p[lblk * 32 + (tid - 32)];

  // B-fragment base pointers (row-major W; compiler remats from L2 per iter --
  // measured cheap, r6/r7). q0 -> k[0:512) (h1 operand); q1 -> k[512:...).
  const unsigned short* w0a = Wp0 + (size_t)(lblk * 32 + lrow) * 832 + (q ? 512 : 0)
                            + (lane >> 4) * 8;
  const unsigned short* w0b = w0a + (size_t)16 * 832;
  const unsigned short* w1a = Wp1 + (size_t)(lblk * 32 + lrow) * 1024 + q * 512
                            + (lane >> 4) * 8;
  const unsigned short* w1b = w1a + (size_t)16 * 1024;
  const int NL0 = q ? 10 : 16;   // L0 frags this khalf (xe pad: 320 = 10 kblks)

  float c1reg = 0.f, c2reg = 0.f;     // cell states: 1 cell/thread/layer
  const int pb = tid >> 3;            // pointwise batch
  const int ph = tid & 7;             // pointwise h-offset
  const size_t hstu = (size_t)(lblk >> 2) * 2048 + (size_t)(pb >> 4) * 512
                    + (size_t)(lblk & 3) * 128 + (size_t)(pb & 15) * 8 + ph;

  for (int t = 0; t <= 512; ++t) {
    // ---- xe prefetch (q1, cached) before the wait ----
    short8 axe[10];
    if (q == 1) {
      const int tx = (t < 512) ? t : 511;      // t=512 L0 inactive; clamp
      const unsigned short* xet = xe + (size_t)tx * 20480;
      #pragma unroll
      for (int j = 0; j < 10; ++j)
        axe[j] = load_frag(xet + (size_t)j * 2048 + (size_t)m * 512 + lane * 8);
    }

    // ---- unified wait: all blocks finished iter t-1 ----
    if (t >= 1) {
      if (wave == 0) {
        int guard = 0;
        for (;;) {
          unsigned v = ld_seq(seq + lane * 16);
          if (__all(v >= (unsigned)t)) break;
          if (++guard > (1 << 18)) break;   // liveness insurance
          __builtin_amdgcn_s_sleep(1);
        }
      }
    }
    __syncthreads();   // S1 (also covers bias_sm init at t=0)

    // ---- h fragment loads (sc1, coalesced) ----
    short8 ah[16];
    if (q == 0) {
      const unsigned short* hA = h1r + (size_t)((t + 1) & 1) * 32768;  // h1(t-1)
      #pragma unroll
      for (int j = 0; j < 16; ++j)
        ah[j] = load_frag_sc1(hA + (size_t)j * 2048 + (size_t)m * 512 + lane * 8);
    } else {
      const unsigned short* hB = h2r + (size_t)(t & 1) * 32768;        // h2(t-2)
      #pragma unroll
      for (int j = 0; j < 16; ++j)
        ah[j] = load_frag_sc1(hB + (size_t)j * 2048 + (size_t)m * 512 + lane * 8);
    }
    asm volatile("s_waitcnt vmcnt(0)" ::: "memory");
    __builtin_amdgcn_sched_barrier(0);

    // ---- MFMA: both layers ----
    f32x4 a00 = {0.f,0.f,0.f,0.f}, a01 = {0.f,0.f,0.f,0.f};   // L0 ntile 0/1
    f32x4 a10 = {0.f,0.f,0.f,0.f}, a11 = {0.f,0.f,0.f,0.f};   // L1 ntile 0/1
    if (q == 0) {
      #pragma unroll
      for (int j = 0; j < 16; ++j) {
        short8 b0 = *(const short8*)(w0a + j * 32);
        short8 b1 = *(const short8*)(w0b + j * 32);
        short8 b2 = *(const short8*)(w1a + j * 32);
        short8 b3 = *(const short8*)(w1b + j * 32);
        a00 = __builtin_amdgcn_mfma_f32_16x16x32_bf16(ah[j], b0, a00, 0, 0, 0);
        a01 = __builtin_amdgcn_mfma_f32_16x16x32_bf16(ah[j], b1, a01, 0, 0, 0);
        a10 = __builtin_amdgcn_mfma_f32_16x16x32_bf16(ah[j], b2, a10, 0, 0, 0);
        a11 = __builtin_amdgcn_mfma_f32_16x16x32_bf16(ah[j], b3, a11, 0, 0, 0);
      }
    } else {
      #pragma unroll
      for (int j = 0; j < 10; ++j) {
        short8 b0 = *(const short8*)(w0a + j * 32);
        short8 b1 = *(const short8*)(w0b + j * 32);
        a00 = __builtin_amdgcn_mfma_f32_16x16x32_bf16(axe[j], b0, a00, 0, 0, 0);
        a01 = __builtin_amdgcn_mfma_f32_16x16x32_bf16(axe[j], b1, a01, 0, 0, 0);
      }
      #pragma unroll
      for (int j = 0; j < 16; ++j) {
        short8 b2 = *(const short8*)(w1a + j * 32);
        short8 b3 = *(const short8*)(w1b + j * 32);
        a10 = __builtin_amdgcn_mfma_f32_16x16x32_bf16(ah[j], b2, a10, 0, 0, 0);
        a11 = __builtin_amdgcn_mfma_f32_16x16x32_bf16(ah[j], b3, a11, 0, 0, 0);
      }
    }
    #pragma unroll
    for (int r = 0; r < 4; ++r) {
      const int bb = m * 16 + (lane >> 4) * 4 + r;
      gl0[q][bb][lrow]      = a00[r];
      gl0[q][bb][16 + lrow] = a01[r];
      gl1[q][bb][lrow]      = a10[r];
      gl1[q][bb][16 + lrow] = a11[r];
    }
    __syncthreads();   // S2: staging complete

    // ---- pointwise: L0 step t, L1 step t-1 ----
    if (t < 512) {
      const float* g0 = gl0[0][pb];
      const float* g1 = gl0[1][pb];
      float gi = g0[ph]      + g1[ph]      + bias0_sm[ph];
      float gf = g0[8 + ph]  + g1[8 + ph]  + bias0_sm[8 + ph];
      float gg = g0[16 + ph] + g1[16 + ph] + bias0_sm[16 + ph];
      float go = g0[24 + ph] + g1[24 + ph] + bias0_sm[24 + ph];
      float iv = sigm(gi), fv = sigm(gf), ov = sigm(go), gv = tanh_f(gg);
      c1reg = fv * c1reg + iv * gv;
      float hv = ov * tanh_f(c1reg);
      unsigned short hb = f2bf(hv);
      unsigned pair = (unsigned)hb | ((unsigned)(unsigned short)__shfl_down((int)hb, 1) << 16);
      if ((ph & 1) == 0)
        st_seq((unsigned*)(h1r + (size_t)(t & 1) * 32768 + hstu), pair);   // h1(t)
    }
    if (t >= 1) {
      const float* g0 = gl1[0][pb];
      const float* g1 = gl1[1][pb];
      float gi = g0[ph]      + g1[ph]      + bias1_sm[ph];
      float gf = g0[8 + ph]  + g1[8 + ph]  + bias1_sm[8 + ph];
      float gg = g0[16 + ph] + g1[16 + ph] + bias1_sm[16 + ph];
      float go = g0[24 + ph] + g1[24 + ph] + bias1_sm[24 + ph];
      float iv = sigm(gi), fv = sigm(gf), ov = sigm(go), gv = tanh_f(gg);
      c2reg = fv * c2reg + iv * gv;
      float hv = ov * tanh_f(c2reg);
      unsigned short hb = f2bf(hv);
      unsigned pair = (unsigned)hb | ((unsigned)(unsigned short)__shfl_down((int)hb, 1) << 16);
      if ((ph & 1) == 0)
        st_seq((unsigned*)(h2r + (size_t)((t + 1) & 1) * 32768 + hstu), pair);  // h2(t-1)
      if (t == 512) c2[pb * HH + lblk * 8 + ph] = c2reg;
    }
    // drain h stores to the coherence point before signaling
    asm volatile("s_waitcnt vmcnt(0)" ::: "memory");
    __syncthreads();   // S3: all waves drained
    if (tid == 0 && t < 512) st_seq(seq + lblk * 16, (unsigned)(t + 1));
  }
}

// ---------------- final projection: out = c2 @ Wout^T + bout ----------------
__global__ void outproj(const float* __restrict__ c2, const float* __restrict__ Wout,
                        const float* __restrict__ bout, float* __restrict__ out)
{
  int t = threadIdx.x;
  if (t >= 640) return;
  int b = t / 10, l = t % 10;
  float s = bout[l];
  #pragma unroll 8
  for (int h = 0; h < 512; ++h) s += c2[b * 512 + h] * Wout[l * 512 + h];
  out[b * 10 + l] = s;
}

extern "C" void kernel_launch(void* const* d_in, const int* in_sizes, int n_in,
                              void* d_out, int out_size, void* d_ws, size_t ws_size,
                              hipStream_t stream) {
  (void)in_sizes; (void)n_in; (void)out_size; (void)ws_size;
  const int*   x    = (const int*)  d_in[0];
  const float* emb  = (const float*)d_in[1];
  const float* Wih0 = (const float*)d_in[2];
  const float* Whh0 = (const float*)d_in[3];
  const float* bih0 = (const float*)d_in[4];
  const float* bhh0 = (const float*)d_in[5];
  const float* Wih1 = (const float*)d_in[6];
  const float* Whh1 = (const float*)d_in[7];
  const float* bih1 = (const float*)d_in[8];
  const float* bhh1 = (const float*)d_in[9];
  const float* Wout = (const float*)d_in[10];
  const float* bout = (const float*)d_in[11];
  float* out = (float*)d_out;

  char* ws = (char*)d_ws;
  unsigned int*   seqb = (unsigned int*)  (ws + OFF_SEQ);
  unsigned short* h1r  = (unsigned short*)(ws + OFF_H1);
  unsigned short* h2r  = (unsigned short*)(ws + OFF_H2);
  float*          c2   = (float*)         (ws + OFF_C2);
  unsigned short* xe   = (unsigned short*)(ws + OFF_XE);
  unsigned short* Wp0  = (unsigned short*)(ws + OFF_W0);
  unsigned short* Wp1  = (unsigned short*)(ws + OFF_W1);
  float*          b0p  = (float*)         (ws + OFF_B0);
  float*          b1p  = (float*)         (ws + OFF_B1);

  hipMemsetAsync(ws, 0, MEMSET_BYTES, stream);   // seq + h rings = 0 (h(-1)=0)
  prep_weights<<<8192, 256, 0, stream>>>(Wih0, Whh0, bih0, bhh0, Wih1, Whh1, bih1, bhh1,
                                         Wp0, Wp1, b0p, b1p);
  gather_xe<<<40960, 256, 0, stream>>>(x, emb, xe);
  lstm_scan<<<64, 512, 0, stream>>>(xe, Wp0, Wp1, b0p, b1p, h1r, h2r, c2, seqb);
  outproj<<<1, 640, 0, stream>>>(c2, Wout, bout, out);
}

// Round 16
// 3119.110 us; speedup vs baseline: 2.6942x; 2.6942x over previous
//
#include <hip/hip_runtime.h>
#include <hip/hip_bf16.h>
#include <stdint.h>

// Problem dims
#define BB 64     // batch
#define SS 512    // seq len
#define HH 512    // hidden
#define DD 300    // embed dim
#define DP 320    // embed dim padded to K%32==0
// Batch groups: 4 independent pipelines of 16 batches each.

typedef __attribute__((ext_vector_type(8))) short short8;      // 8 x bf16
typedef __attribute__((ext_vector_type(4))) float f32x4;

__device__ __forceinline__ unsigned short f2bf(float f) {
  unsigned u = __builtin_bit_cast(unsigned, f);
  u += 0x7fffu + ((u >> 16) & 1u);       // RNE
  return (unsigned short)(u >> 16);
}
__device__ __forceinline__ float sigm(float x) { return 1.f / (1.f + __expf(-x)); }
__device__ __forceinline__ float tanh_f(float x) {
  float t = __expf(-2.f * fabsf(x));
  float r = (1.f - t) / (1.f + t);
  return x < 0.f ? -r : r;
}

// 16B loads. sc1 = agent scope (MALL-coherent). NOT valid until s_waitcnt vmcnt(0).
__device__ __forceinline__ short8 load_frag(const unsigned short* p) {
  short8 r;
  asm volatile("global_load_dwordx4 %0, %1, off" : "=v"(r) : "v"(p));
  return r;
}
__device__ __forceinline__ short8 load_frag_sc1(const unsigned short* p) {
  short8 r;
  asm volatile("global_load_dwordx4 %0, %1, off sc1" : "=v"(r) : "v"(p));
  return r;
}
__device__ __forceinline__ unsigned ld_seq(const unsigned int* p) {
  return __hip_atomic_load(p, __ATOMIC_RELAXED, __HIP_MEMORY_SCOPE_AGENT);
}
__device__ __forceinline__ void st_seq(unsigned int* p, unsigned v) {
  __hip_atomic_store(p, v, __ATOMIC_RELAXED, __HIP_MEMORY_SCOPE_AGENT);
}

// ---------------- workspace layout (bytes) ----------------
// Per-group h panels are [16 batches][512 hidden] bf16 = 8192 u16 = 16KB.
// Frag-ready (r16 FIX: kblk stride is 512 u16, NOT 1024 -- r14/r15 aliased
// ring slots and overran xe into Wp0): element (b, c) at u16 addr
// (c>>5)*512 + (((c>>3)&3)*16 + b)*8 + (c&7); panel span = 15*512+511 = 8191.
// MFMA A-frag (kblk) = kblk*512 + lane*8 (row = lane&15 = batch,
// k = kblk*32 + (lane>>4)*8 + e).
// h1: ring-4 per group (L0 writes slot t&3; L1 reads slot t&3; L0 reads
// (t+3)&3; safety via l1seq >= t-3). h2: ring-2 per group (L1 only).
#define OFF_H1SEQ 0u          // [4 groups][32 blocks] u32, 64B spaced -> 8192
#define OFF_L1SEQ 8192u       // same -> 16384
#define OFF_H1    16384u      // [4 g][4 slots][8192 u16] -> 262144 (ends 278528)
#define OFF_H2    278528u     // [4 g][2 slots][8192 u16] -> 131072 (ends 409600)
#define OFF_C2    409600u     // c2 [64][512] f32 -> 131072 (ends 540672)
#define OFF_XE    540672u     // xe [512 t][4 g][10 kblk][512 u16] -> 20971520
#define OFF_W0    21512192u   // Wp0 [2048][832] bf16 -> 3407872
#define OFF_W1    24920064u   // Wp1 [2048][1024] bf16 -> 4194304
#define OFF_B0    29114368u   // bias0p [2048] f32 -> 8192
#define OFF_B1    29122560u   // bias1p [2048] f32 -> 8192 (ends 29130752)
#define MEMSET_BYTES 409600u  // seqs + h1 + h2 (zeros; h(-1)=0 slots included)

// ---------------- weight prep (row-major Wp, slice-major rows) ----------------
// Row grow = s*64 + nt*16 + lr (s = cell-slice [0,32), nt = gate i/f/g/o,
// lr = cell offset [0,16)); orig = nt*512 + s*16 + lr.
// Wp0 row: [ W_hh0 | W_ih0 | pad to 832 ] (A = [h1_prev | x_t]);
// Wp1 row: [ W_ih1 | W_hh1 ]             (A = [h1_t | h2_prev]).
__global__ void prep_weights(const float* __restrict__ Wih0, const float* __restrict__ Whh0,
                             const float* __restrict__ bih0, const float* __restrict__ bhh0,
                             const float* __restrict__ Wih1, const float* __restrict__ Whh1,
                             const float* __restrict__ bih1, const float* __restrict__ bhh1,
                             unsigned short* __restrict__ Wp0, unsigned short* __restrict__ Wp1,
                             float* __restrict__ b0p, float* __restrict__ b1p)
{
  int idx = blockIdx.x * 256 + threadIdx.x;   // over 2048*1024
  int grow = idx >> 10;
  int k1 = idx & 1023;
  int s  = grow >> 6;
  int nt = (grow >> 4) & 3;
  int lr = grow & 15;
  int orig = nt * 512 + s * 16 + lr;
  float v1 = (k1 < 512) ? Wih1[orig * 512 + k1] : Whh1[orig * 512 + (k1 - 512)];
  Wp1[grow * 1024 + k1] = f2bf(v1);
  if (k1 < 832) {
    float v0;
    if (k1 < 512)      v0 = Whh0[orig * 512 + k1];
    else if (k1 < 812) v0 = Wih0[orig * 300 + (k1 - 512)];
    else               v0 = 0.f;
    Wp0[grow * 832 + k1] = f2bf(v0);
  }
  if (k1 == 0) {
    b0p[grow] = bih0[orig] + bhh0[orig];
    b1p[grow] = bih1[orig] + bhh1[orig];
  }
}

// ---------------- embedding gather -> per-group frag layout ----------------
__global__ void gather_xe(const int* __restrict__ x, const float* __restrict__ emb,
                          unsigned short* __restrict__ xe)
{
  int idx = blockIdx.x * 256 + threadIdx.x;   // SS*BB*DP = 10485760
  int dk = idx % DP;
  int rem = idx / DP;
  int b = rem % BB;
  int t = rem / BB;
  int tok = x[b * SS + t];
  float v = (dk < DD) ? emb[(size_t)tok * DD + dk] : 0.f;
  int g = b >> 4, br = b & 15;
  size_t ua = (size_t)t * 20480 + (size_t)g * 5120 + (size_t)(dk >> 5) * 512
            + (size_t)((((dk >> 3) & 3) << 4) + br) * 8 + (dk & 7);   // r16: *512
  xe[ua] = f2bf(v);
}

// ---------------- unified persistent scan (256 blocks x 512 thr) ----------------
// blk<128: L0 (g=(blk>>5)&3, s=blk&31); else L1. Per block: 16 cells (s*16..+16)
// of its group's 16 batches; 8 waves split K (4 kblks each), every wave computes
// all 4 gate-ntiles for its kblks; LDS-staged 8-partial reduce in pointwise.
// Protocol per group = r9 exactly (store-only seqs, sleep-backed polls).
__attribute__((amdgpu_waves_per_eu(2, 2)))
__global__ void __launch_bounds__(512)
lstm_scan(const unsigned short* __restrict__ xe,
          const unsigned short* __restrict__ Wp0,
          const unsigned short* __restrict__ Wp1,
          const float* __restrict__ b0p, const float* __restrict__ b1p,
          unsigned short* __restrict__ h1r, unsigned short* __restrict__ h2r,
          float* __restrict__ c2, unsigned int* __restrict__ seqbase)
{
  __shared__ float gl[8][16][68];   // [wave][batch][gate col 0..63] (+pad)
  __shared__ float bias_sm[64];

  const int blk  = blockIdx.x;
  const bool isL0 = blk < 128;
  const int g = (blk >> 5) & 3;
  const int s = blk & 31;
  const int tid = threadIdx.x;
  const int lane = tid & 63;
  const int w    = tid >> 6;
  const int lrow = lane & 15;

  if (tid < 64) bias_sm[tid] = (isL0 ? b0p : b1p)[s * 64 + tid];

  const int K = isL0 ? 832 : 1024;
  const unsigned short* wbase = (isL0 ? Wp0 : Wp1)
                              + (size_t)(s * 64 + lrow) * K + (lane >> 4) * 8;

  unsigned short* h1g = h1r + (size_t)g * 4 * 8192;
  unsigned short* h2g = h2r + (size_t)g * 2 * 8192;
  unsigned int* h1sq = (unsigned int*)seqbase + (size_t)g * 32 * 16;          // group h1 seqs
  unsigned int* l1sq = (unsigned int*)seqbase + 2048 + (size_t)g * 32 * 16;   // byte 8192

  // per-wave kblk assignment
  int js0, nj;
  if (isL0) {
    if (w < 4) { js0 = w * 4; nj = 4; }                       // h1 kblks 0..15
    else { int w4 = w - 4; js0 = (w4 < 2) ? w4 * 3 : 6 + (w4 - 2) * 2;
           nj = (w4 < 2) ? 3 : 2; }                           // xe kblks 0..9
  } else {
    js0 = (w & 3) * 4; nj = 4;   // w<4: h1(t) kblks 0..15; w>=4: h2 kblks 0..15
  }

  float creg = 0.f;                   // cell state (threads tid<256)
  const int pb = (tid >> 4) & 15;     // pointwise local batch
  const int ph = tid & 15;            // pointwise cell offset
  const int cc = s * 16 + ph;         // hidden index in group panel
  const size_t hstu = (size_t)(cc >> 5) * 512
                    + (size_t)((((cc >> 3) & 3) << 4) + pb) * 8 + (cc & 7);   // r16: *512

  for (int t = 0; t < 512; ++t) {
    short8 a[4];
    f32x4 acc[4] = {{0.f,0.f,0.f,0.f},{0.f,0.f,0.f,0.f},
                    {0.f,0.f,0.f,0.f},{0.f,0.f,0.f,0.f}};

    if (isL0) {
      // ---- xe prefetch (waves 4-7, cached) before the wait ----
      if (w >= 4) {
        const unsigned short* xet = xe + (size_t)t * 20480 + (size_t)g * 5120;
        #pragma unroll
        for (int i = 0; i < 4; ++i)
          if (i < nj) a[i] = load_frag(xet + (size_t)(js0 + i) * 512 + lane * 8);  // r16
      }
      // ---- wait: group peers done t-1; L1 group >= t-3 (ring-4 safety) ----
      if (t >= 1 && w == 0) {
        int guard = 0;
        for (;;) {
          unsigned v; bool ok;
          if (lane < 32) { v = ld_seq(h1sq + lane * 16); ok = v >= (unsigned)t; }
          else           { v = ld_seq(l1sq + (lane - 32) * 16); ok = (int)v >= t - 3; }
          if (__all(ok)) break;
          if (++guard > (1 << 18)) break;
          __builtin_amdgcn_s_sleep(1);
        }
      }
      __syncthreads();   // S1
      // ---- h1(t-1) loads (waves 0-3, sc1) ----
      if (w < 4) {
        const unsigned short* hp = h1g + (size_t)((t + 3) & 3) * 8192;
        #pragma unroll
        for (int i = 0; i < 4; ++i)
          a[i] = load_frag_sc1(hp + (size_t)(js0 + i) * 512 + lane * 8);   // r16
      }
      // ALL waves drain their outstanding loads (xe or h1) here (r15 fix).
      asm volatile("s_waitcnt vmcnt(0)" ::: "memory");
      __builtin_amdgcn_sched_barrier(0);
      // ---- MFMA: 4 ntiles x nj kblks ----
      #pragma unroll
      for (int i = 0; i < 4; ++i) {
        if (i < nj) {
          const int kb = (w < 4) ? (js0 + i) : (16 + js0 + i);
          #pragma unroll
          for (int nt = 0; nt < 4; ++nt) {
            short8 bf = *(const short8*)(wbase + (size_t)nt * 16 * 832 + (size_t)kb * 32);
            acc[nt] = __builtin_amdgcn_mfma_f32_16x16x32_bf16(a[i], bf, acc[nt], 0, 0, 0);
          }
        }
      }
      #pragma unroll
      for (int nt = 0; nt < 4; ++nt)
        #pragma unroll
        for (int r = 0; r < 4; ++r)
          gl[w][(lane >> 4) * 4 + r][nt * 16 + lrow] = acc[nt][r];
      __syncthreads();   // S2
      // ---- pointwise + h1(t) store ----
      if (tid < 256) {
        float gi = bias_sm[ph], gf = bias_sm[16 + ph],
              gg = bias_sm[32 + ph], go = bias_sm[48 + ph];
        #pragma unroll
        for (int w8 = 0; w8 < 8; ++w8) {
          gi += gl[w8][pb][ph];      gf += gl[w8][pb][16 + ph];
          gg += gl[w8][pb][32 + ph]; go += gl[w8][pb][48 + ph];
        }
        float iv = sigm(gi), fv = sigm(gf), ov = sigm(go), gv = tanh_f(gg);
        creg = fv * creg + iv * gv;
        float hv = ov * tanh_f(creg);
        unsigned short hb = f2bf(hv);
        unsigned pair = (unsigned)hb | ((unsigned)(unsigned short)__shfl_down((int)hb, 1) << 16);
        if ((ph & 1) == 0)
          st_seq((unsigned*)(h1g + (size_t)(t & 3) * 8192 + hstu), pair);
      }
      asm volatile("s_waitcnt vmcnt(0)" ::: "memory");   // drain h1 stores
      __syncthreads();   // S3
      if (tid == 0) st_seq(h1sq + s * 16, (unsigned)(t + 1));
    } else {
      // ---- L1: phase A: wait h1(t) ----
      if (w == 0) {
        int guard = 0;
        for (;;) {
          unsigned v = (lane < 32) ? ld_seq(h1sq + lane * 16) : (unsigned)(t + 1);
          if (__all(v >= (unsigned)(t + 1))) break;
          if (++guard > (1 << 18)) break;
          __builtin_amdgcn_s_sleep(1);
        }
      }
      __syncthreads();   // S1
      if (w < 4) {
        // h1(t) half (off the h2 recurrence) while wave4 polls l1seq
        const unsigned short* hp = h1g + (size_t)(t & 3) * 8192;
        #pragma unroll
        for (int i = 0; i < 4; ++i)
          a[i] = load_frag_sc1(hp + (size_t)(js0 + i) * 512 + lane * 8);   // r16
        asm volatile("s_waitcnt vmcnt(0)" ::: "memory");
        __builtin_amdgcn_sched_barrier(0);
        #pragma unroll
        for (int i = 0; i < 4; ++i) {
          const int kb = js0 + i;
          #pragma unroll
          for (int nt = 0; nt < 4; ++nt) {
            short8 bf = *(const short8*)(wbase + (size_t)nt * 16 * 1024 + (size_t)kb * 32);
            acc[nt] = __builtin_amdgcn_mfma_f32_16x16x32_bf16(a[i], bf, acc[nt], 0, 0, 0);
          }
        }
        #pragma unroll
        for (int nt = 0; nt < 4; ++nt)
          #pragma unroll
          for (int r = 0; r < 4; ++r)
            gl[w][(lane >> 4) * 4 + r][nt * 16 + lrow] = acc[nt][r];
      } else if (w == 4 && t >= 1) {
        int guard = 0;
        for (;;) {
          unsigned v = (lane < 32) ? ld_seq(l1sq + lane * 16) : (unsigned)t;
          if (__all(v >= (unsigned)t)) break;
          if (++guard > (1 << 18)) break;
          __builtin_amdgcn_s_sleep(1);
        }
      }
      __syncthreads();   // S2: h2(t-1) ready everywhere
      if (w >= 4) {
        const unsigned short* hp = h2g + (size_t)((t + 1) & 1) * 8192;
        #pragma unroll
        for (int i = 0; i < 4; ++i)
          a[i] = load_frag_sc1(hp + (size_t)(js0 + i) * 512 + lane * 8);   // r16
        asm volatile("s_waitcnt vmcnt(0)" ::: "memory");
        __builtin_amdgcn_sched_barrier(0);
        #pragma unroll
        for (int i = 0; i < 4; ++i) {
          const int kb = 16 + js0 + i;
          #pragma unroll
          for (int nt = 0; nt < 4; ++nt) {
            short8 bf = *(const short8*)(wbase + (size_t)nt * 16 * 1024 + (size_t)kb * 32);
            acc[nt] = __builtin_amdgcn_mfma_f32_16x16x32_bf16(a[i], bf, acc[nt], 0, 0, 0);
          }
        }
        #pragma unroll
        for (int nt = 0; nt < 4; ++nt)
          #pragma unroll
          for (int r = 0; r < 4; ++r)
            gl[w][(lane >> 4) * 4 + r][nt * 16 + lrow] = acc[nt][r];
      }
      __syncthreads();   // S3
      if (tid < 256) {
        float gi = bias_sm[ph], gf = bias_sm[16 + ph],
              gg = bias_sm[32 + ph], go = bias_sm[48 + ph];
        #pragma unroll
        for (int w8 = 0; w8 < 8; ++w8) {
          gi += gl[w8][pb][ph];      gf += gl[w8][pb][16 + ph];
          gg += gl[w8][pb][32 + ph]; go += gl[w8][pb][48 + ph];
        }
        float iv = sigm(gi), fv = sigm(gf), ov = sigm(go), gv = tanh_f(gg);
        creg = fv * creg + iv * gv;
        float hv = ov * tanh_f(creg);
        unsigned short hb = f2bf(hv);
        unsigned pair = (unsigned)hb | ((unsigned)(unsigned short)__shfl_down((int)hb, 1) << 16);
        if ((ph & 1) == 0)
          st_seq((unsigned*)(h2g + (size_t)(t & 1) * 8192 + hstu), pair);
        if (t == 511) c2[(size_t)(g * 16 + pb) * HH + s * 16 + ph] = creg;
      }
      asm volatile("s_waitcnt vmcnt(0)" ::: "memory");   // drain h2 stores
      __syncthreads();   // S4
      if (tid == 0) st_seq(l1sq + s * 16, (unsigned)(t + 1));
    }
  }
}

// ---------------- final projection: out = c2 @ Wout^T + bout ----------------
__global__ void outproj(const float* __restrict__ c2, const float* __restrict__ Wout,
                        const float* __restrict__ bout, float* __restrict__ out)
{
  int t = threadIdx.x;
  if (t >= 640) return;
  int b = t / 10, l = t % 10;
  float s = bout[l];
  #pragma unroll 8
  for (int h = 0; h < 512; ++h) s += c2[b * 512 + h] * Wout[l * 512 + h];
  out[b * 10 + l] = s;
}

extern "C" void kernel_launch(void* const* d_in, const int* in_sizes, int n_in,
                              void* d_out, int out_size, void* d_ws, size_t ws_size,
                              hipStream_t stream) {
  (void)in_sizes; (void)n_in; (void)out_size; (void)ws_size;
  const int*   x    = (const int*)  d_in[0];
  const float* emb  = (const float*)d_in[1];
  const float* Wih0 = (const float*)d_in[2];
  const float* Whh0 = (const float*)d_in[3];
  const float* bih0 = (const float*)d_in[4];
  const float* bhh0 = (const float*)d_in[5];
  const float* Wih1 = (const float*)d_in[6];
  const float* Whh1 = (const float*)d_in[7];
  const float* bih1 = (const float*)d_in[8];
  const float* bhh1 = (const float*)d_in[9];
  const float* Wout = (const float*)d_in[10];
  const float* bout = (const float*)d_in[11];
  float* out = (float*)d_out;

  char* ws = (char*)d_ws;
  unsigned int*   seqb = (unsigned int*)  (ws + OFF_H1SEQ);
  unsigned short* h1r  = (unsigned short*)(ws + OFF_H1);
  unsigned short* h2r  = (unsigned short*)(ws + OFF_H2);
  float*          c2   = (float*)         (ws + OFF_C2);
  unsigned short* xe   = (unsigned short*)(ws + OFF_XE);
  unsigned short* Wp0  = (unsigned short*)(ws + OFF_W0);
  unsigned short* Wp1  = (unsigned short*)(ws + OFF_W1);
  float*          b0p  = (float*)         (ws + OFF_B0);
  float*          b1p  = (float*)         (ws + OFF_B1);

  hipMemsetAsync(ws, 0, MEMSET_BYTES, stream);   // seqs + h rings (h(-1)=0)
  prep_weights<<<8192, 256, 0, stream>>>(Wih0, Whh0, bih0, bhh0, Wih1, Whh1, bih1, bhh1,
                                         Wp0, Wp1, b0p, b1p);
  gather_xe<<<40960, 256, 0, stream>>>(x, emb, xe);
  lstm_scan<<<256, 512, 0, stream>>>(xe, Wp0, Wp1, b0p, b1p, h1r, h2r, c2, seqb);
  outproj<<<1, 640, 0, stream>>>(c2, Wout, bout, out);
}

// Round 17
// 1850.779 us; speedup vs baseline: 4.5406x; 1.6853x over previous
//
#include <hip/hip_runtime.h>
#include <hip/hip_bf16.h>
#include <stdint.h>

// Problem dims
#define BB 64     // batch
#define SS 512    // seq len
#define HH 512    // hidden
#define DD 300    // embed dim
#define DP 320    // embed dim padded to K%32==0

typedef __attribute__((ext_vector_type(8))) short short8;  // 8 x bf16
typedef __attribute__((ext_vector_type(4))) float f32x4;

__device__ __forceinline__ unsigned short f2bf(float f) {
  unsigned u = __builtin_bit_cast(unsigned, f);
  u += 0x7fffu + ((u >> 16) & 1u);       // RNE
  return (unsigned short)(u >> 16);
}
__device__ __forceinline__ float sigm(float x) { return 1.f / (1.f + __expf(-x)); }
__device__ __forceinline__ float tanh_f(float x) {
  float t = __expf(-2.f * fabsf(x));
  float r = (1.f - t) / (1.f + t);
  return x < 0.f ? -r : r;
}

// Coalesced 16B loads (lane l reads base + l*16). sc1 -> agent-scope (MALL-coherent).
// Results NOT valid until an explicit s_waitcnt vmcnt(0)!
__device__ __forceinline__ short8 load_frag_sc1(const unsigned short* p) {
  short8 r;
  asm volatile("global_load_dwordx4 %0, %1, off sc1" : "=v"(r) : "v"(p));
  return r;
}
__device__ __forceinline__ short8 load_frag(const unsigned short* p) {
  short8 r;
  asm volatile("global_load_dwordx4 %0, %1, off" : "=v"(r) : "v"(p));
  return r;
}
__device__ __forceinline__ unsigned ld_seq(const unsigned int* p) {
  return __hip_atomic_load(p, __ATOMIC_RELAXED, __HIP_MEMORY_SCOPE_AGENT);
}
__device__ __forceinline__ void st_seq(unsigned int* p, unsigned v) {
  __hip_atomic_store(p, v, __ATOMIC_RELAXED, __HIP_MEMORY_SCOPE_AGENT);
}

// ---------------- workspace layout (bytes) ----------------
// Frag-ready layouts: element (b, c) of a [64 x 32*NKB] bf16 panel lives at
// 2B-unit addr: (c>>5)*2048 + (b>>4)*512 + ((c>>3)&3)*128 + (b&15)*8 + (c&7)
// so MFMA A-frag (mtile m, kblk) = base + kblk*2048 + m*512 + lane*8, 16B/lane.
// Sync: store-only seq words (NO atomics). h1seq[64] @0 (64B spaced),
// l1seq[64] @4096. seq[b] = number of steps block b has completed.
#define OFF_SEQ   0u          // 2 x 64 words x 64B -> 8192
#define OFF_H1    8192u       // h1 ring [4][64KB frag-layout] -> 262144
#define OFF_H2    270336u     // h2 ring [2][64KB frag-layout] -> 131072
#define OFF_C2    401408u     // c2 [64][512] f32 -> 131072
#define OFF_XE    532480u     // xe frag-layout [512][10 kblk][4KB] -> 20971520
#define OFF_W0    21504000u   // Wp0 [2048][832] bf16 -> 3407872
#define OFF_W1    24911872u   // Wp1 [2048][1024] bf16 -> 4194304
#define OFF_B0    29106176u   // bias0p [2048] f32
#define OFF_B1    29114368u   // bias1p [2048] f32
#define MEMSET_BYTES 401408u  // seqs + h1 ring + h2 ring

// ---------------- weight prep (row-major Wp, round-6 layout) ----------------
// Row reorder: grow = lblk*32 + l, gate = l>>3 (i,f,g,o), orig = gate*512 + lblk*8 + (l&7).
// Wp0 row: [ W_hh0 | W_ih0 | pad ] (A = [h1_prev | x_t]); Wp1 row: [ W_ih1 | W_hh1 ].
__global__ void prep_weights(const float* __restrict__ Wih0, const float* __restrict__ Whh0,
                             const float* __restrict__ bih0, const float* __restrict__ bhh0,
                             const float* __restrict__ Wih1, const float* __restrict__ Whh1,
                             const float* __restrict__ bih1, const float* __restrict__ bhh1,
                             unsigned short* __restrict__ Wp0, unsigned short* __restrict__ Wp1,
                             float* __restrict__ b0p, float* __restrict__ b1p)
{
  int idx = blockIdx.x * 256 + threadIdx.x;   // over 2048*1024
  int grow = idx >> 10;
  int k1 = idx & 1023;
  int l = grow & 31;
  int lb = grow >> 5;
  int gate = l >> 3;
  int orig = gate * 512 + lb * 8 + (l & 7);
  float v1 = (k1 < 512) ? Wih1[orig * 512 + k1] : Whh1[orig * 512 + (k1 - 512)];
  Wp1[idx] = f2bf(v1);
  if (k1 < 832) {
    float v0;
    if (k1 < 512)      v0 = Whh0[orig * 512 + k1];
    else if (k1 < 812) v0 = Wih0[orig * 300 + (k1 - 512)];
    else               v0 = 0.f;
    Wp0[grow * 832 + k1] = f2bf(v0);
  }
  if (k1 == 0) {
    b0p[grow] = bih0[orig] + bhh0[orig];
    b1p[grow] = bih1[orig] + bhh1[orig];
  }
}

// ---------------- embedding gather -> frag-ready layout ----------------
__global__ void gather_xe(const int* __restrict__ x, const float* __restrict__ emb,
                          unsigned short* __restrict__ xe)
{
  int idx = blockIdx.x * 256 + threadIdx.x;   // SS*BB*DP = 10485760
  int dk = idx % DP;
  int rem = idx / DP;
  int b = rem % BB;
  int t = rem / BB;
  int tok = x[b * SS + t];
  float v = (dk < DD) ? emb[(size_t)tok * DD + dk] : 0.f;
  size_t ua = (size_t)t * 20480 + (size_t)(dk >> 5) * 2048 + (size_t)(b >> 4) * 512
            + (size_t)((dk >> 3) & 3) * 128 + (size_t)(b & 15) * 8 + (dk & 7);
  xe[ua] = f2bf(v);
}

// ---------------- layer-0 persistent scan (64 blocks) ----------------
// Step t: reads h1(t-1) [slot (t+3)&3] + xe(t), writes h1(t) [slot t&3].
// Wait: all h1seq >= t (peers done t-1) AND all l1seq >= t-3 (ring-4 back-pressure).
__device__ __forceinline__ void scan_l0(
    int lblk,
    const unsigned short* __restrict__ xe,
    const unsigned short* __restrict__ Wp,
    const float* __restrict__ biasP,
    unsigned short* __restrict__ h1r,
    unsigned int* h1seq, unsigned int* l1seq,
    float (&gl)[2][64][36], float (&bias_sm)[32])
{
  constexpr int K = 832, NK = 13;
  const int tid  = threadIdx.x;
  const int lane = tid & 63;
  const int wave = tid >> 6;
  const int lrow = lane & 15;
  const int m    = wave & 3;
  const int q    = wave >> 2;
  const int qkb  = q * NK;

  if (tid < 32) bias_sm[tid] = biasP[lblk * 32 + tid];

  short8 Bf0[NK], Bf1[NK];
  {
    const unsigned short* wr0 = Wp + (size_t)(lblk * 32 + lrow) * K + qkb * 32 + (lane >> 4) * 8;
    const unsigned short* wr1 = wr0 + (size_t)16 * K;
    #pragma unroll
    for (int j = 0; j < NK; ++j) {
      Bf0[j] = *(const short8*)(wr0 + j * 32);
      Bf1[j] = *(const short8*)(wr1 + j * 32);
    }
  }
  #pragma unroll
  for (int j = 0; j < NK; ++j) asm volatile("" : "+v"(Bf0[j]), "+v"(Bf1[j]));

  float creg = 0.f;
  const int pb = tid >> 3;
  const int ph = tid & 7;
  const size_t hst = (size_t)(lblk >> 2) * 2048 + (size_t)(pb >> 4) * 512
                   + (size_t)(lblk & 3) * 128 + (size_t)(pb & 15) * 8 + ph;

  for (int t = 0; t < 512; ++t) {
    short8 a[NK];
    // xe prefetch (cached) before the wait
    {
      const unsigned short* xet = xe + (size_t)t * 20480;
      #pragma unroll
      for (int j = 0; j < NK; ++j) {
        const int kg = qkb + j;
        if (kg >= 16)
          a[j] = load_frag(xet + (size_t)(kg - 16) * 2048 + (size_t)m * 512 + lane * 8);
      }
    }
    if (t >= 1) {
      if (wave == 0) {
        int guard = 0;
        for (;;) {
          unsigned v1 = ld_seq(h1seq + lane * 16);
          unsigned v2 = ld_seq(l1seq + lane * 16);
          bool ok = (v1 >= (unsigned)t) && ((int)v2 >= t - 3);
          if (__all(ok)) break;
          if (++guard > (1 << 20)) break;   // liveness insurance
          __builtin_amdgcn_s_sleep(1);
        }
      }
      __syncthreads();
    }
    // h1(t-1) fragment loads (sc1, coalesced)
    {
      const unsigned short* hA = h1r + (size_t)((t + 3) & 3) * 32768;
      #pragma unroll
      for (int j = 0; j < NK; ++j) {
        const int kg = qkb + j;
        if (kg < 16)
          a[j] = load_frag_sc1(hA + (size_t)kg * 2048 + (size_t)m * 512 + lane * 8);
      }
    }
    asm volatile("s_waitcnt vmcnt(0)" ::: "memory");
    __builtin_amdgcn_sched_barrier(0);

    f32x4 acc0 = {0.f, 0.f, 0.f, 0.f};
    f32x4 acc1 = {0.f, 0.f, 0.f, 0.f};
    #pragma unroll
    for (int j = 0; j < NK; ++j) {
      acc0 = __builtin_amdgcn_mfma_f32_16x16x32_bf16(a[j], Bf0[j], acc0, 0, 0, 0);
      acc1 = __builtin_amdgcn_mfma_f32_16x16x32_bf16(a[j], Bf1[j], acc1, 0, 0, 0);
    }
    #pragma unroll
    for (int r = 0; r < 4; ++r) {
      const int bb = m * 16 + (lane >> 4) * 4 + r;
      gl[q][bb][lrow]      = acc0[r];
      gl[q][bb][16 + lrow] = acc1[r];
    }
    __syncthreads();
    {
      float gi = gl[0][pb][ph]      + gl[1][pb][ph]      + bias_sm[ph];
      float gf = gl[0][pb][8 + ph]  + gl[1][pb][8 + ph]  + bias_sm[8 + ph];
      float gg = gl[0][pb][16 + ph] + gl[1][pb][16 + ph] + bias_sm[16 + ph];
      float go = gl[0][pb][24 + ph] + gl[1][pb][24 + ph] + bias_sm[24 + ph];
      float iv = sigm(gi), fv = sigm(gf), ov = sigm(go), gv = tanh_f(gg);
      creg = fv * creg + iv * gv;
      float hv = ov * tanh_f(creg);
      unsigned short hb = f2bf(hv);
      unsigned pair = (unsigned)hb | ((unsigned)(unsigned short)__shfl_down((int)hb, 1) << 16);
      unsigned short* hw = h1r + (size_t)(t & 3) * 32768 + hst;
      if ((ph & 1) == 0)
        st_seq((unsigned*)hw, pair);
    }
    asm volatile("s_waitcnt vmcnt(0)" ::: "memory");   // h visible before seq
    __syncthreads();
    if (tid == 0) st_seq(h1seq + lblk * 16, (unsigned)(t + 1));
  }
}

// ---------------- layer-1 persistent scan (64 blocks) ----------------
// Step t: reads h1(t) [slot t&3] + h2(t-1) [slot (t+1)&1], writes h2(t) [slot t&1].
// r17 restructure: BOTH polls run pre-S1 on separate waves (wave0: h1seq>=t+1;
// wave4: l1seq>=t); S2 deleted; q0 (h1 half) and q1 (h2 half) load+MFMA
// CONCURRENTLY between S1 and S3. Removes q0's work from the h2-recurrence
// critical chain (r9 serialized q1 behind q0 via S2 for no dependency reason).
__device__ __forceinline__ void scan_l1(
    int lblk,
    const unsigned short* __restrict__ Wp,
    const float* __restrict__ biasP,
    const unsigned short* __restrict__ h1r,
    unsigned short* __restrict__ h2r,
    float* __restrict__ c2,
    unsigned int* h1seq, unsigned int* l1seq,
    float (&gl)[2][64][36], float (&bias_sm)[32])
{
  constexpr int K = 1024, NK = 16;
  const int tid  = threadIdx.x;
  const int lane = tid & 63;
  const int wave = tid >> 6;
  const int lrow = lane & 15;
  const int m    = wave & 3;
  const int q    = wave >> 2;
  const int qkb  = q * NK;

  if (tid < 32) bias_sm[tid] = biasP[lblk * 32 + tid];

  short8 Bf0[NK], Bf1[NK];
  {
    const unsigned short* wr0 = Wp + (size_t)(lblk * 32 + lrow) * K + qkb * 32 + (lane >> 4) * 8;
    const unsigned short* wr1 = wr0 + (size_t)16 * K;
    #pragma unroll
    for (int j = 0; j < NK; ++j) {
      Bf0[j] = *(const short8*)(wr0 + j * 32);
      Bf1[j] = *(const short8*)(wr1 + j * 32);
    }
  }
  #pragma unroll
  for (int j = 0; j < NK; ++j) asm volatile("" : "+v"(Bf0[j]), "+v"(Bf1[j]));

  float creg = 0.f;
  const int pb = tid >> 3;
  const int ph = tid & 7;
  const size_t hst = (size_t)(lblk >> 2) * 2048 + (size_t)(pb >> 4) * 512
                   + (size_t)(lblk & 3) * 128 + (size_t)(pb & 15) * 8 + ph;

  for (int t = 0; t < 512; ++t) {
    // ---- dual pre-S1 polls (concurrent on different waves) ----
    if (wave == 0) {
      int guard = 0;
      for (;;) {
        unsigned v = ld_seq(h1seq + lane * 16);
        if (__all(v >= (unsigned)(t + 1))) break;
        if (++guard > (1 << 20)) break;
        __builtin_amdgcn_s_sleep(1);
      }
    } else if (wave == 4 && t >= 1) {
      int guard = 0;
      for (;;) {
        unsigned v = ld_seq(l1seq + lane * 16);
        if (__all(v >= (unsigned)t)) break;
        if (++guard > (1 << 20)) break;
        __builtin_amdgcn_s_sleep(1);
      }
    }
    __syncthreads();   // S1: h1(t) ready AND h2(t-1) ready

    // ---- q0 (h1 half) and q1 (h2 half) run CONCURRENTLY ----
    {
      const unsigned short* hp = (q == 0)
          ? (h1r + (size_t)(t & 3) * 32768)          // h1(t)
          : (h2r + (size_t)((t + 1) & 1) * 32768);   // h2(t-1)
      short8 a[NK];
      #pragma unroll
      for (int j = 0; j < NK; ++j)
        a[j] = load_frag_sc1(hp + (size_t)j * 2048 + (size_t)m * 512 + lane * 8);
      asm volatile("s_waitcnt vmcnt(0)" ::: "memory");
      __builtin_amdgcn_sched_barrier(0);
      f32x4 acc0 = {0.f, 0.f, 0.f, 0.f};
      f32x4 acc1 = {0.f, 0.f, 0.f, 0.f};
      #pragma unroll
      for (int j = 0; j < NK; ++j) {
        acc0 = __builtin_amdgcn_mfma_f32_16x16x32_bf16(a[j], Bf0[j], acc0, 0, 0, 0);
        acc1 = __builtin_amdgcn_mfma_f32_16x16x32_bf16(a[j], Bf1[j], acc1, 0, 0, 0);
      }
      #pragma unroll
      for (int r = 0; r < 4; ++r) {
        const int bb = m * 16 + (lane >> 4) * 4 + r;
        gl[q][bb][lrow]      = acc0[r];
        gl[q][bb][16 + lrow] = acc1[r];
      }
    }
    __syncthreads();   // S3: both gl halves staged

    {
      float gi = gl[0][pb][ph]      + gl[1][pb][ph]      + bias_sm[ph];
      float gf = gl[0][pb][8 + ph]  + gl[1][pb][8 + ph]  + bias_sm[8 + ph];
      float gg = gl[0][pb][16 + ph] + gl[1][pb][16 + ph] + bias_sm[16 + ph];
      float go = gl[0][pb][24 + ph] + gl[1][pb][24 + ph] + bias_sm[24 + ph];
      float iv = sigm(gi), fv = sigm(gf), ov = sigm(go), gv = tanh_f(gg);
      creg = fv * creg + iv * gv;
      float hv = ov * tanh_f(creg);
      unsigned short hb = f2bf(hv);
      unsigned pair = (unsigned)hb | ((unsigned)(unsigned short)__shfl_down((int)hb, 1) << 16);
      unsigned short* hw = h2r + (size_t)(t & 1) * 32768 + hst;
      if ((ph & 1) == 0)
        st_seq((unsigned*)hw, pair);
      if (t == 511) c2[pb * HH + lblk * 8 + ph] = creg;
    }
    asm volatile("s_waitcnt vmcnt(0)" ::: "memory");   // h2 visible before seq
    __syncthreads();   // S4
    if (tid == 0) st_seq(l1seq + lblk * 16, (unsigned)(t + 1));
  }
}

__attribute__((amdgpu_waves_per_eu(2, 2)))
__global__ void __launch_bounds__(512)
lstm_scan(const unsigned short* __restrict__ xe,
          const unsigned short* __restrict__ Wp0,
          const unsigned short* __restrict__ Wp1,
          const float* __restrict__ b0p, const float* __restrict__ b1p,
          unsigned short* __restrict__ h1r, unsigned short* __restrict__ h2r,
          float* __restrict__ c2, unsigned int* __restrict__ seqbase)
{
  __shared__ float gl[2][64][36];
  __shared__ float bias_sm[32];
  unsigned int* h1seq = seqbase;
  unsigned int* l1seq = seqbase + 1024;   // byte 4096
  const int blk = blockIdx.x;
  if (blk < 64) scan_l0(blk,      xe, Wp0, b0p, h1r, h1seq, l1seq, gl, bias_sm);
  else          scan_l1(blk - 64, Wp1, b1p, h1r, h2r, c2, h1seq, l1seq, gl, bias_sm);
}

// ---------------- final projection: out = c2 @ Wout^T + bout ----------------
__global__ void outproj(const float* __restrict__ c2, const float* __restrict__ Wout,
                        const float* __restrict__ bout, float* __restrict__ out)
{
  int t = threadIdx.x;
  if (t >= 640) return;
  int b = t / 10, l = t % 10;
  float s = bout[l];
  #pragma unroll 8
  for (int h = 0; h < 512; ++h) s += c2[b * 512 + h] * Wout[l * 512 + h];
  out[b * 10 + l] = s;
}

extern "C" void kernel_launch(void* const* d_in, const int* in_sizes, int n_in,
                              void* d_out, int out_size, void* d_ws, size_t ws_size,
                              hipStream_t stream) {
  (void)in_sizes; (void)n_in; (void)out_size; (void)ws_size;
  const int*   x    = (const int*)  d_in[0];
  const float* emb  = (const float*)d_in[1];
  const float* Wih0 = (const float*)d_in[2];
  const float* Whh0 = (const float*)d_in[3];
  const float* bih0 = (const float*)d_in[4];
  const float* bhh0 = (const float*)d_in[5];
  const float* Wih1 = (const float*)d_in[6];
  const float* Whh1 = (const float*)d_in[7];
  const float* bih1 = (const float*)d_in[8];
  const float* bhh1 = (const float*)d_in[9];
  const float* Wout = (const float*)d_in[10];
  const float* bout = (const float*)d_in[11];
  float* out = (float*)d_out;

  char* ws = (char*)d_ws;
  unsigned int*   seqb = (unsigned int*)  (ws + OFF_SEQ);
  unsigned short* h1r  = (unsigned short*)(ws + OFF_H1);
  unsigned short* h2r  = (unsigned short*)(ws + OFF_H2);
  float*          c2   = (float*)         (ws + OFF_C2);
  unsigned short* xe   = (unsigned short*)(ws + OFF_XE);
  unsigned short* Wp0  = (unsigned short*)(ws + OFF_W0);
  unsigned short* Wp1  = (unsigned short*)(ws + OFF_W1);
  float*          b0p  = (float*)         (ws + OFF_B0);
  float*          b1p  = (float*)         (ws + OFF_B1);

  hipMemsetAsync(ws, 0, MEMSET_BYTES, stream);   // seqs + h rings = 0
  prep_weights<<<8192, 256, 0, stream>>>(Wih0, Whh0, bih0, bhh0, Wih1, Whh1, bih1, bhh1,
                                         Wp0, Wp1, b0p, b1p);
  gather_xe<<<40960, 256, 0, stream>>>(x, emb, xe);
  lstm_scan<<<128, 512, 0, stream>>>(xe, Wp0, Wp1, b0p, b1p, h1r, h2r, c2, seqb);
  outproj<<<1, 640, 0, stream>>>(c2, Wout, bout, out);
}

// Round 20
// 1849.884 us; speedup vs baseline: 4.5427x; 1.0005x over previous
//
#include <hip/hip_runtime.h>
#include <hip/hip_bf16.h>
#include <stdint.h>

// Problem dims
#define BB 64     // batch
#define SS 512    // seq len
#define HH 512    // hidden
#define DD 300    // embed dim
#define DP 320    // embed dim padded to K%32==0

typedef __attribute__((ext_vector_type(8))) short short8;  // 8 x bf16
typedef __attribute__((ext_vector_type(4))) float f32x4;

__device__ __forceinline__ unsigned short f2bf(float f) {
  unsigned u = __builtin_bit_cast(unsigned, f);
  u += 0x7fffu + ((u >> 16) & 1u);       // RNE
  return (unsigned short)(u >> 16);
}
__device__ __forceinline__ float sigm(float x) { return 1.f / (1.f + __expf(-x)); }
__device__ __forceinline__ float tanh_f(float x) {
  float t = __expf(-2.f * fabsf(x));
  float r = (1.f - t) / (1.f + t);
  return x < 0.f ? -r : r;
}

// Coalesced 16B loads (lane l reads base + l*16). sc1 -> agent-scope (MALL-coherent).
// Results NOT valid until an explicit s_waitcnt vmcnt(0)!
__device__ __forceinline__ short8 load_frag_sc1(const unsigned short* p) {
  short8 r;
  asm volatile("global_load_dwordx4 %0, %1, off sc1" : "=v"(r) : "v"(p));
  return r;
}
__device__ __forceinline__ short8 load_frag(const unsigned short* p) {
  short8 r;
  asm volatile("global_load_dwordx4 %0, %1, off" : "=v"(r) : "v"(p));
  return r;
}
__device__ __forceinline__ unsigned ld_seq(const unsigned int* p) {
  return __hip_atomic_load(p, __ATOMIC_RELAXED, __HIP_MEMORY_SCOPE_AGENT);
}
__device__ __forceinline__ void st_seq(unsigned int* p, unsigned v) {
  __hip_atomic_store(p, v, __ATOMIC_RELAXED, __HIP_MEMORY_SCOPE_AGENT);
}

// ---------------- workspace layout (bytes) ----------------
// Frag-ready layouts: element (b, c) of a [64 x 32*NKB] bf16 panel lives at
// 2B-unit addr: (c>>5)*2048 + (b>>4)*512 + ((c>>3)&3)*128 + (b&15)*8 + (c&7)
// so MFMA A-frag (mtile m, kblk) = base + kblk*2048 + m*512 + lane*8, 16B/lane.
// Sync: store-only seq words (NO atomics). h1seq[64] @0 (64B spaced),
// l1seq[64] @4096. seq[b] = number of steps block b has completed.
#define OFF_SEQ   0u          // 2 x 64 words x 64B -> 8192
#define OFF_H1    8192u       // h1 ring [4][64KB frag-layout] -> 262144
#define OFF_H2    270336u     // h2 ring [2][64KB frag-layout] -> 131072
#define OFF_C2    401408u     // c2 [64][512] f32 -> 131072
#define OFF_XE    532480u     // xe frag-layout [512][10 kblk][4KB] -> 20971520
#define OFF_W0    21504000u   // Wp0 [2048][832] bf16 -> 3407872
#define OFF_W1    24911872u   // Wp1 [2048][1024] bf16 -> 4194304
#define OFF_B0    29106176u   // bias0p [2048] f32
#define OFF_B1    29114368u   // bias1p [2048] f32
#define MEMSET_BYTES 401408u  // seqs + h1 ring + h2 ring

// ---------------- weight prep (row-major Wp) ----------------
// Row reorder: grow = lblk*32 + l, gate = l>>3 (i,f,g,o), orig = gate*512 + lblk*8 + (l&7).
// Wp0 row: [ W_hh0 | W_ih0 | pad ] (A = [h1_prev | x_t]); Wp1 row: [ W_ih1 | W_hh1 ].
__global__ void prep_weights(const float* __restrict__ Wih0, const float* __restrict__ Whh0,
                             const float* __restrict__ bih0, const float* __restrict__ bhh0,
                             const float* __restrict__ Wih1, const float* __restrict__ Whh1,
                             const float* __restrict__ bih1, const float* __restrict__ bhh1,
                             unsigned short* __restrict__ Wp0, unsigned short* __restrict__ Wp1,
                             float* __restrict__ b0p, float* __restrict__ b1p)
{
  int idx = blockIdx.x * 256 + threadIdx.x;   // over 2048*1024
  int grow = idx >> 10;
  int k1 = idx & 1023;
  int l = grow & 31;
  int lb = grow >> 5;
  int gate = l >> 3;
  int orig = gate * 512 + lb * 8 + (l & 7);
  float v1 = (k1 < 512) ? Wih1[orig * 512 + k1] : Whh1[orig * 512 + (k1 - 512)];
  Wp1[idx] = f2bf(v1);
  if (k1 < 832) {
    float v0;
    if (k1 < 512)      v0 = Whh0[orig * 512 + k1];
    else if (k1 < 812) v0 = Wih0[orig * 300 + (k1 - 512)];
    else               v0 = 0.f;
    Wp0[grow * 832 + k1] = f2bf(v0);
  }
  if (k1 == 0) {
    b0p[grow] = bih0[orig] + bhh0[orig];
    b1p[grow] = bih1[orig] + bhh1[orig];
  }
}

// ---------------- embedding gather -> frag-ready layout ----------------
__global__ void gather_xe(const int* __restrict__ x, const float* __restrict__ emb,
                          unsigned short* __restrict__ xe)
{
  int idx = blockIdx.x * 256 + threadIdx.x;   // SS*BB*DP = 10485760
  int dk = idx % DP;
  int rem = idx / DP;
  int b = rem % BB;
  int t = rem / BB;
  int tok = x[b * SS + t];
  float v = (dk < DD) ? emb[(size_t)tok * DD + dk] : 0.f;
  size_t ua = (size_t)t * 20480 + (size_t)(dk >> 5) * 2048 + (size_t)(b >> 4) * 512
            + (size_t)((dk >> 3) & 3) * 128 + (size_t)(b & 15) * 8 + (dk & 7);
  xe[ua] = f2bf(v);
}

// ---------------- layer-0 persistent scan (64 blocks) ----------------
// Step t: reads h1(t-1) [slot (t+3)&3] + xe(t), writes h1(t) [slot t&3].
// Wait: all h1seq >= t (peers done t-1) AND all l1seq >= t-3 (ring-4 back-pressure).
__device__ __forceinline__ void scan_l0(
    int lblk,
    const unsigned short* __restrict__ xe,
    const unsigned short* __restrict__ Wp,
    const float* __restrict__ biasP,
    unsigned short* __restrict__ h1r,
    unsigned int* h1seq, unsigned int* l1seq,
    float (&gl)[2][64][36], float (&bias_sm)[32])
{
  constexpr int K = 832, NK = 13;
  const int tid  = threadIdx.x;
  const int lane = tid & 63;
  const int wave = tid >> 6;
  const int lrow = lane & 15;
  const int m    = wave & 3;
  const int q    = wave >> 2;
  const int qkb  = q * NK;

  if (tid < 32) bias_sm[tid] = biasP[lblk * 32 + tid];

  short8 Bf0[NK], Bf1[NK];
  {
    const unsigned short* wr0 = Wp + (size_t)(lblk * 32 + lrow) * K + qkb * 32 + (lane >> 4) * 8;
    const unsigned short* wr1 = wr0 + (size_t)16 * K;
    #pragma unroll
    for (int j = 0; j < NK; ++j) {
      Bf0[j] = *(const short8*)(wr0 + j * 32);
      Bf1[j] = *(const short8*)(wr1 + j * 32);
    }
  }
  #pragma unroll
  for (int j = 0; j < NK; ++j) asm volatile("" : "+v"(Bf0[j]), "+v"(Bf1[j]));

  float creg = 0.f;
  const int pb = tid >> 3;
  const int ph = tid & 7;
  const size_t hst = (size_t)(lblk >> 2) * 2048 + (size_t)(pb >> 4) * 512
                   + (size_t)(lblk & 3) * 128 + (size_t)(pb & 15) * 8 + ph;

  for (int t = 0; t < 512; ++t) {
    short8 a[NK];
    // xe prefetch (cached) before the wait
    {
      const unsigned short* xet = xe + (size_t)t * 20480;
      #pragma unroll
      for (int j = 0; j < NK; ++j) {
        const int kg = qkb + j;
        if (kg >= 16)
          a[j] = load_frag(xet + (size_t)(kg - 16) * 2048 + (size_t)m * 512 + lane * 8);
      }
    }
    if (t >= 1) {
      if (wave == 0) {
        int guard = 0;
        for (;;) {
          unsigned v1 = ld_seq(h1seq + lane * 16);
          unsigned v2 = ld_seq(l1seq + lane * 16);
          bool ok = (v1 >= (unsigned)t) && ((int)v2 >= t - 3);
          if (__all(ok)) break;
          if (++guard > (1 << 20)) break;   // liveness insurance
          __builtin_amdgcn_s_sleep(1);
        }
      }
      __syncthreads();
    }
    // h1(t-1) fragment loads (sc1, coalesced)
    {
      const unsigned short* hA = h1r + (size_t)((t + 3) & 3) * 32768;
      #pragma unroll
      for (int j = 0; j < NK; ++j) {
        const int kg = qkb + j;
        if (kg < 16)
          a[j] = load_frag_sc1(hA + (size_t)kg * 2048 + (size_t)m * 512 + lane * 8);
      }
    }
    asm volatile("s_waitcnt vmcnt(0)" ::: "memory");
    __builtin_amdgcn_sched_barrier(0);

    f32x4 acc0 = {0.f, 0.f, 0.f, 0.f};
    f32x4 acc1 = {0.f, 0.f, 0.f, 0.f};
    #pragma unroll
    for (int j = 0; j < NK; ++j) {
      acc0 = __builtin_amdgcn_mfma_f32_16x16x32_bf16(a[j], Bf0[j], acc0, 0, 0, 0);
      acc1 = __builtin_amdgcn_mfma_f32_16x16x32_bf16(a[j], Bf1[j], acc1, 0, 0, 0);
    }
    #pragma unroll
    for (int r = 0; r < 4; ++r) {
      const int bb = m * 16 + (lane >> 4) * 4 + r;
      gl[q][bb][lrow]      = acc0[r];
      gl[q][bb][16 + lrow] = acc1[r];
    }
    __syncthreads();
    {
      float gi = gl[0][pb][ph]      + gl[1][pb][ph]      + bias_sm[ph];
      float gf = gl[0][pb][8 + ph]  + gl[1][pb][8 + ph]  + bias_sm[8 + ph];
      float gg = gl[0][pb][16 + ph] + gl[1][pb][16 + ph] + bias_sm[16 + ph];
      float go = gl[0][pb][24 + ph] + gl[1][pb][24 + ph] + bias_sm[24 + ph];
      float iv = sigm(gi), fv = sigm(gf), ov = sigm(go), gv = tanh_f(gg);
      creg = fv * creg + iv * gv;
      float hv = ov * tanh_f(creg);
      unsigned short hb = f2bf(hv);
      unsigned pair = (unsigned)hb | ((unsigned)(unsigned short)__shfl_down((int)hb, 1) << 16);
      unsigned short* hw = h1r + (size_t)(t & 3) * 32768 + hst;
      if ((ph & 1) == 0)
        st_seq((unsigned*)hw, pair);
    }
    asm volatile("s_waitcnt vmcnt(0)" ::: "memory");   // h visible before seq
    __syncthreads();
    if (tid == 0) st_seq(h1seq + lblk * 16, (unsigned)(t + 1));
  }
}

// ---------------- layer-1 persistent scan (64 blocks) ----------------
// Step t: reads h1(t) [slot t&3] + h2(t-1) [slot (t+1)&1], writes h2(t) [slot t&1].
// BOTH polls run pre-S1 on separate waves (wave0: h1seq>=t+1; wave4: l1seq>=t);
// q0 (h1 half) and q1 (h2 half) load+MFMA CONCURRENTLY between S1 and S3.
__device__ __forceinline__ void scan_l1(
    int lblk,
    const unsigned short* __restrict__ Wp,
    const float* __restrict__ biasP,
    const unsigned short* __restrict__ h1r,
    unsigned short* __restrict__ h2r,
    float* __restrict__ c2,
    unsigned int* h1seq, unsigned int* l1seq,
    float (&gl)[2][64][36], float (&bias_sm)[32])
{
  constexpr int K = 1024, NK = 16;
  const int tid  = threadIdx.x;
  const int lane = tid & 63;
  const int wave = tid >> 6;
  const int lrow = lane & 15;
  const int m    = wave & 3;
  const int q    = wave >> 2;
  const int qkb  = q * NK;

  if (tid < 32) bias_sm[tid] = biasP[lblk * 32 + tid];

  short8 Bf0[NK], Bf1[NK];
  {
    const unsigned short* wr0 = Wp + (size_t)(lblk * 32 + lrow) * K + qkb * 32 + (lane >> 4) * 8;
    const unsigned short* wr1 = wr0 + (size_t)16 * K;
    #pragma unroll
    for (int j = 0; j < NK; ++j) {
      Bf0[j] = *(const short8*)(wr0 + j * 32);
      Bf1[j] = *(const short8*)(wr1 + j * 32);
    }
  }
  #pragma unroll
  for (int j = 0; j < NK; ++j) asm volatile("" : "+v"(Bf0[j]), "+v"(Bf1[j]));

  float creg = 0.f;
  const int pb = tid >> 3;
  const int ph = tid & 7;
  const size_t hst = (size_t)(lblk >> 2) * 2048 + (size_t)(pb >> 4) * 512
                   + (size_t)(lblk & 3) * 128 + (size_t)(pb & 15) * 8 + ph;

  for (int t = 0; t < 512; ++t) {
    // ---- dual pre-S1 polls (concurrent on different waves) ----
    if (wave == 0) {
      int guard = 0;
      for (;;) {
        unsigned v = ld_seq(h1seq + lane * 16);
        if (__all(v >= (unsigned)(t + 1))) break;
        if (++guard > (1 << 20)) break;
        __builtin_amdgcn_s_sleep(1);
      }
    } else if (wave == 4 && t >= 1) {
      int guard = 0;
      for (;;) {
        unsigned v = ld_seq(l1seq + lane * 16);
        if (__all(v >= (unsigned)t)) break;
        if (++guard > (1 << 20)) break;
        __builtin_amdgcn_s_sleep(1);
      }
    }
    __syncthreads();   // S1: h1(t) ready AND h2(t-1) ready

    // ---- q0 (h1 half) and q1 (h2 half) run CONCURRENTLY ----
    {
      const unsigned short* hp = (q == 0)
          ? (h1r + (size_t)(t & 3) * 32768)          // h1(t)
          : (h2r + (size_t)((t + 1) & 1) * 32768);   // h2(t-1)
      short8 a[NK];
      #pragma unroll
      for (int j = 0; j < NK; ++j)
        a[j] = load_frag_sc1(hp + (size_t)j * 2048 + (size_t)m * 512 + lane * 8);
      asm volatile("s_waitcnt vmcnt(0)" ::: "memory");
      __builtin_amdgcn_sched_barrier(0);
      f32x4 acc0 = {0.f, 0.f, 0.f, 0.f};
      f32x4 acc1 = {0.f, 0.f, 0.f, 0.f};
      #pragma unroll
      for (int j = 0; j < NK; ++j) {
        acc0 = __builtin_amdgcn_mfma_f32_16x16x32_bf16(a[j], Bf0[j], acc0, 0, 0, 0);
        acc1 = __builtin_amdgcn_mfma_f32_16x16x32_bf16(a[j], Bf1[j], acc1, 0, 0, 0);
      }
      #pragma unroll
      for (int r = 0; r < 4; ++r) {
        const int bb = m * 16 + (lane >> 4) * 4 + r;
        gl[q][bb][lrow]      = acc0[r];
        gl[q][bb][16 + lrow] = acc1[r];
      }
    }
    __syncthreads();   // S3: both gl halves staged

    {
      float gi = gl[0][pb][ph]      + gl[1][pb][ph]      + bias_sm[ph];
      float gf = gl[0][pb][8 + ph]  + gl[1][pb][8 + ph]  + bias_sm[8 + ph];
      float gg = gl[0][pb][16 + ph] + gl[1][pb][16 + ph] + bias_sm[16 + ph];
      float go = gl[0][pb][24 + ph] + gl[1][pb][24 + ph] + bias_sm[24 + ph];
      float iv = sigm(gi), fv = sigm(gf), ov = sigm(go), gv = tanh_f(gg);
      creg = fv * creg + iv * gv;
      float hv = ov * tanh_f(creg);
      unsigned short hb = f2bf(hv);
      unsigned pair = (unsigned)hb | ((unsigned)(unsigned short)__shfl_down((int)hb, 1) << 16);
      unsigned short* hw = h2r + (size_t)(t & 1) * 32768 + hst;
      if ((ph & 1) == 0)
        st_seq((unsigned*)hw, pair);
      if (t == 511) c2[pb * HH + lblk * 8 + ph] = creg;
    }
    asm volatile("s_waitcnt vmcnt(0)" ::: "memory");   // h2 visible before seq
    __syncthreads();   // S4
    if (tid == 0) st_seq(l1seq + lblk * 16, (unsigned)(t + 1));
  }
}

__attribute__((amdgpu_waves_per_eu(2, 2)))
__global__ void __launch_bounds__(512)
lstm_scan(const unsigned short* __restrict__ xe,
          const unsigned short* __restrict__ Wp0,
          const unsigned short* __restrict__ Wp1,
          const float* __restrict__ b0p, const float* __restrict__ b1p,
          unsigned short* __restrict__ h1r, unsigned short* __restrict__ h2r,
          float* __restrict__ c2, unsigned int* __restrict__ seqbase)
{
  __shared__ float gl[2][64][36];
  __shared__ float bias_sm[32];
  unsigned int* h1seq = seqbase;
  unsigned int* l1seq = seqbase + 1024;   // byte 4096
  const int blk = blockIdx.x;
  if (blk < 64) scan_l0(blk,      xe, Wp0, b0p, h1r, h1seq, l1seq, gl, bias_sm);
  else          scan_l1(blk - 64, Wp1, b1p, h1r, h2r, c2, h1seq, l1seq, gl, bias_sm);
}

// ---------------- final projection: out = c2 @ Wout^T + bout ----------------
__global__ void outproj(const float* __restrict__ c2, const float* __restrict__ Wout,
                        const float* __restrict__ bout, float* __restrict__ out)
{
  int t = threadIdx.x;
  if (t >= 640) return;
  int b = t / 10, l = t % 10;
  float s = bout[l];
  #pragma unroll 8
  for (int h = 0; h < 512; ++h) s += c2[b * 512 + h] * Wout[l * 512 + h];
  out[b * 10 + l] = s;
}

extern "C" void kernel_launch(void* const* d_in, const int* in_sizes, int n_in,
                              void* d_out, int out_size, void* d_ws, size_t ws_size,
                              hipStream_t stream) {
  (void)in_sizes; (void)n_in; (void)out_size; (void)ws_size;
  const int*   x    = (const int*)  d_in[0];
  const float* emb  = (const float*)d_in[1];
  const float* Wih0 = (const float*)d_in[2];
  const float* Whh0 = (const float*)d_in[3];
  const float* bih0 = (const float*)d_in[4];
  const float* bhh0 = (const float*)d_in[5];
  const float* Wih1 = (const float*)d_in[6];
  const float* Whh1 = (const float*)d_in[7];
  const float* bih1 = (const float*)d_in[8];
  const float* bhh1 = (const float*)d_in[9];
  const float* Wout = (const float*)d_in[10];
  const float* bout = (const float*)d_in[11];
  float* out = (float*)d_out;

  char* ws = (char*)d_ws;
  unsigned int*   seqb = (unsigned int*)  (ws + OFF_SEQ);
  unsigned short* h1r  = (unsigned short*)(ws + OFF_H1);
  unsigned short* h2r  = (unsigned short*)(ws + OFF_H2);
  float*          c2   = (float*)         (ws + OFF_C2);
  unsigned short* xe   = (unsigned short*)(ws + OFF_XE);
  unsigned short* Wp0  = (unsigned short*)(ws + OFF_W0);
  unsigned short* Wp1  = (unsigned short*)(ws + OFF_W1);
  float*          b0p  = (float*)         (ws + OFF_B0);
  float*          b1p  = (float*)         (ws + OFF_B1);

  hipMemsetAsync(ws, 0, MEMSET_BYTES, stream);   // seqs + h rings = 0
  prep_weights<<<8192, 256, 0, stream>>>(Wih0, Whh0, bih0, bhh0, Wih1, Whh1, bih1, bhh1,
                                         Wp0, Wp1, b0p, b1p);
  gather_xe<<<40960, 256, 0, stream>>>(x, emb, xe);
  lstm_scan<<<128, 512, 0, stream>>>(xe, Wp0, Wp1, b0p, b1p, h1r, h2r, c2, seqb);
  outproj<<<1, 640, 0, stream>>>(c2, Wout, bout, out);
}